// Round 7
// baseline (3882.079 us; speedup 1.0000x reference)
//
#include <hip/hip_runtime.h>
#include <cmath>

// PhaseAwareClassifier on MI355X — R7: split-bf16 MFMA, spill+conflict fix.
// R6 post-mortem: (512,4) -> VGPR=64 -> massive scratch spills (7.7GB fetch);
// O[n][k] LDS layout -> 8-way bank conflicts (1.06e8).
// R7: (512,2) -> 128-VGPR cap, no spills. Chunked layouts:
//   LDS  O[mat][kchunk c][n=64][8]  -> lane stride 16B -> 2-way (free).
//   conn A[mat][kchunk c][m=160][8] -> coalesced 16B/lane fragment loads.
// Prep pre-negates -Ci (2 extra matrices) so no runtime sign flip.
// Math identical to R6 (validated absmax 0.0): acc == 4*field invariant,
// x = bf16_hi + bf16_lo split, C*O ~= Chh + Chl + Clh in fp32 MFMA.

#define NSTEPS  10
#define INJ_ST  4

typedef __bf16 bf16x8 __attribute__((ext_vector_type(8)));
typedef __bf16 bf16x4 __attribute__((ext_vector_type(4)));
typedef float  f32x4  __attribute__((ext_vector_type(4)));

// workspace layout (float offsets)
#define WS_MAX    0          // 1      enc_max (uint-ordered float)
#define WS_ENERGY 64         // 1280   energy[b][10]
#define WS_GSP    2048       // 160    softplus(gain), zero-padded
#define WS_CONN   4096       // 6 bf16 matrices [20][160][8] chunked:
                             //   0:Crh 1:Crl 2:Cih 3:Cil 4:-Cih 5:-Cil
                             //   6*25600 bf16 = 76800 floats
#define WS_INJ    81920      // 100352 inj[b][49][16] = px * 1.02/enc_max

__global__ void k_init(float* ws) {
    int i = blockIdx.x * 256 + threadIdx.x;
    if (i == 0) ws[WS_MAX] = 0.f;
    if (i < 1280) ws[WS_ENERGY + i] = 0.f;
}

__global__ void k_max(const float* __restrict__ img, float* ws, int n) {
    __shared__ float sm[256];
    float v = 0.f;
    for (int i = blockIdx.x * blockDim.x + threadIdx.x; i < n; i += gridDim.x * blockDim.x)
        v = fmaxf(v, fabsf(img[i]));
    sm[threadIdx.x] = v;
    __syncthreads();
    for (int s = 128; s > 0; s >>= 1) {
        if (threadIdx.x < s) sm[threadIdx.x] = fmaxf(sm[threadIdx.x], sm[threadIdx.x + s]);
        __syncthreads();
    }
    if (threadIdx.x == 0)
        atomicMax((unsigned int*)(ws + WS_MAX), __float_as_uint(sm[0]));
}

__global__ void k_prep(const float* __restrict__ img,
                       const float* __restrict__ cr, const float* __restrict__ ci,
                       const float* __restrict__ phase, const float* __restrict__ gain,
                       float* ws) {
    int i = blockIdx.x * 256 + threadIdx.x;
    __bf16* Cb = (__bf16*)(ws + WS_CONN);
    if (i < 25600) {                       // (m=j row, k=s col) of A
        int m = i / 160, k = i % 160;
        float vr = 0.f, vi = 0.f;
        if (m < 131 && k < 131) {
            float a = cr[k * 131 + m], b = ci[k * 131 + m];
            float ph = phase[m];
            float cp = cosf(ph), sp = sinf(ph);
            vr = a * cp - b * sp;
            vi = a * sp + b * cp;
        }
        __bf16 rh = (__bf16)vr;  __bf16 rl = (__bf16)(vr - (float)rh);
        __bf16 ih = (__bf16)vi;  __bf16 il = (__bf16)(vi - (float)ih);
        int ca = ((k >> 3) * 160 + m) * 8 + (k & 7);   // chunked addr
        Cb[ca]             = rh;
        Cb[25600 * 1 + ca] = rl;
        Cb[25600 * 2 + ca] = ih;
        Cb[25600 * 3 + ca] = il;
        Cb[25600 * 4 + ca] = -ih;
        Cb[25600 * 5 + ca] = -il;
    } else if (i < 25760) {
        int j = i - 25600;
        float g = 0.f;
        if (j < 131) {
            float x = gain[j];
            g = (x > 20.f) ? x : log1pf(expf(x));  // softplus
        }
        ws[WS_GSP + j] = g;                 // zero for padded rows -> out=0
    } else if (i < 25760 + 128 * 49 * 16) {
        int q = i - 25760;
        int m = q & 15, jj = (q >> 4) % 49, b = q / (49 * 16);
        int u = m >> 2, v2 = m & 3, pi = jj / 7, pj = jj % 7;
        float px = img[b * 784 + (pi * 4 + u) * 28 + (pj * 4 + v2)];
        float mx = ws[WS_MAX];
        float sc = (mx > 1e-8f) ? (1.02f / mx) : 1.02f;   // 0.85*4*0.3
        ws[WS_INJ + q] = px * sc;
    }
}

static __device__ __forceinline__ f32x4 MF(bf16x8 a, bf16x8 b, f32x4 c) {
    return __builtin_amdgcn_mfma_f32_16x16x32_bf16(a, b, c, 0, 0, 0);
}

__global__ __launch_bounds__(512, 2)
void k_main(const float* __restrict__ ws, float* __restrict__ energy) {
    // O state: 4 bf16 matrices chunked [c=20][n=64][8]: rh, rl, ih, il
    __shared__ __bf16 OB[4][20 * 64 * 8];          // 81,920 B -> 2 blocks/CU
    const int tid  = threadIdx.x;
    const int lane = tid & 63;
    const int ln15 = lane & 15;
    const int quad = lane >> 4;
    const int wv   = __builtin_amdgcn_readfirstlane(tid >> 6);  // 0..7
    const int ntile = wv & 3;
    const int mhalf = wv >> 2;
    const int nidx  = ntile * 16 + ln15;            // this lane's column 0..63
    const int c = blockIdx.x * 64 + nidx;
    const int b = c >> 10;
    const int l = (c >> 4) & 63;
    const int m = c & 15;
    const float wl = 1.0f - fabsf((float)l - 32.0f) * (1.0f / 64.0f);

    const __bf16* __restrict__ Cb  = (const __bf16*)(ws + WS_CONN);
    const float* __restrict__ gsp  = ws + WS_GSP;
    const float* __restrict__ injb = ws + WS_INJ;

    __bf16* __restrict__ OBrh = &OB[0][0];
    __bf16* __restrict__ OBrl = &OB[1][0];
    __bf16* __restrict__ OBih = &OB[2][0];
    __bf16* __restrict__ OBil = &OB[3][0];

    f32x4 accr[5], acci[5];                         // acc == 4 * field
#pragma unroll
    for (int p = 0; p < 5; ++p) { accr[p] = (f32x4)0.f; acci[p] = (f32x4)0.f; }

    // zero O state
    {
        int* obi = (int*)&OB[0][0];
        for (int i = tid; i < 20480; i += 512) obi[i] = 0;
    }

    // injection: field += inj  =>  acc += (4*inj); values pre-scaled so that
    // adding AFTER the 0.85 multiply matches reference (1.02 = 0.85*4*0.3)
    auto inj_add = [&]() {
        if (mhalf == 0) {
#pragma unroll
            for (int p = 0; p < 4; ++p) {           // tiles 0..3 cover j<64
#pragma unroll
                for (int r = 0; r < 4; ++r) {
                    int j = p * 16 + quad * 4 + r;
                    if (j < 49) accr[p][r] += injb[(b * 49 + j) * 16 + m] * wl;
                }
            }
        }
    };

    // epilogue: out = tanh-rescale(0.25*acc), split hi/lo, chunked LDS write
    auto epilogue = [&]() {
#pragma unroll
        for (int p = 0; p < 5; ++p) {
            const int j0 = (mhalf * 5 + p) * 16 + quad * 4;
            float g4[4];
            *(float4*)g4 = *(const float4*)(gsp + j0);
            bf16x4 prh, prl, pih, pil;
#pragma unroll
            for (int r = 0; r < 4; ++r) {
                float fr = accr[p][r] * 0.25f;
                float fi = acci[p][r] * 0.25f;
                float mag = sqrtf(fr * fr + fi * fi + 1e-8f);
                float y = mag * g4[r];
                float e = __expf(-2.0f * y);
                float th = 1.0f - 2.0f * e * __builtin_amdgcn_rcpf(1.0f + e);
                float scv = th * __builtin_amdgcn_rcpf(mag + 1e-8f);
                float orv = fr * scv, oiv = fi * scv;
                __bf16 h;
                h = (__bf16)orv; prh[r] = h; prl[r] = (__bf16)(orv - (float)h);
                h = (__bf16)oiv; pih[r] = h; pil[r] = (__bf16)(oiv - (float)h);
            }
            // chunked write: chunk = j0>>3, elem offset = j0&7 (0 or 4)
            const int off = ((j0 >> 3) * 64 + nidx) * 8 + (j0 & 7);
            *(bf16x4*)(OBrh + off) = prh;
            *(bf16x4*)(OBrl + off) = prl;
            *(bf16x4*)(OBih + off) = pih;
            *(bf16x4*)(OBil + off) = pil;
        }
    };

    __syncthreads();
    inj_add();                                      // t = 0 (g term is zero)
    epilogue();
    __syncthreads();

    for (int t = 1; t < NSTEPS; ++t) {
        // decay pre-scale + injection
#pragma unroll
        for (int p = 0; p < 5; ++p) { accr[p] *= 0.85f; acci[p] *= 0.85f; }
        if (t < INJ_ST) inj_add();

        // ---- MFMA phase: G += C * O (complex, split-bf16) ----
#pragma unroll
        for (int kt = 0; kt < 5; ++kt) {
            const int ch = kt * 4 + quad;           // this lane's k-chunk
            const int boff = (ch * 64 + nidx) * 8;
            bf16x8 b_rh = *(const bf16x8*)(OBrh + boff);
            bf16x8 b_rl = *(const bf16x8*)(OBrl + boff);
            bf16x8 b_ih = *(const bf16x8*)(OBih + boff);
            bf16x8 b_il = *(const bf16x8*)(OBil + boff);
#pragma unroll
            for (int p = 0; p < 5; ++p) {
                const int mr = (mhalf * 5 + p) * 16 + ln15;
                const int aoff = (ch * 160 + mr) * 8;
                bf16x8 a_rh  = *(const bf16x8*)(Cb + aoff);
                bf16x8 a_rl  = *(const bf16x8*)(Cb + 25600 * 1 + aoff);
                bf16x8 a_ih  = *(const bf16x8*)(Cb + 25600 * 2 + aoff);
                bf16x8 a_il  = *(const bf16x8*)(Cb + 25600 * 3 + aoff);
                bf16x8 a_nih = *(const bf16x8*)(Cb + 25600 * 4 + aoff);
                bf16x8 a_nil = *(const bf16x8*)(Cb + 25600 * 5 + aoff);
                f32x4 ar = accr[p], ai = acci[p];
                // G_r += Cr*Or - Ci*Oi
                ar = MF(a_rh, b_rh, ar); ar = MF(a_rh, b_rl, ar); ar = MF(a_rl, b_rh, ar);
                ar = MF(a_nih, b_ih, ar); ar = MF(a_nih, b_il, ar); ar = MF(a_nil, b_ih, ar);
                // G_i += Cr*Oi + Ci*Or
                ai = MF(a_rh, b_ih, ai); ai = MF(a_rh, b_il, ai); ai = MF(a_rl, b_ih, ai);
                ai = MF(a_ih, b_rh, ai); ai = MF(a_ih, b_rl, ai); ai = MF(a_il, b_rh, ai);
                accr[p] = ar; acci[p] = ai;
            }
        }
        __syncthreads();   // all reads of OB done
        epilogue();
        __syncthreads();   // OB ready for next step
    }

    // ---- energy: j = 121..130, sum over this block's 64 cols ----
    float v0 = 0.f, v1 = 0.f;
    {
        int e0 = tid >> 6, c0 = tid & 63, j = 121 + e0;
        int o = ((j >> 3) * 64 + c0) * 8 + (j & 7);
        float orv = (float)OBrh[o] + (float)OBrl[o];
        float oiv = (float)OBih[o] + (float)OBil[o];
        v0 = orv * orv + oiv * oiv;
        if (tid < 128) {
            int i1 = tid + 512;
            int e1 = i1 >> 6, c1 = i1 & 63; j = 121 + e1;
            o = ((j >> 3) * 64 + c1) * 8 + (j & 7);
            orv = (float)OBrh[o] + (float)OBrl[o];
            oiv = (float)OBih[o] + (float)OBil[o];
            v1 = orv * orv + oiv * oiv;
        }
    }
    __syncthreads();
    float* scr = (float*)&OB[0][0];
    scr[tid] = v0;
    if (tid < 128) scr[tid + 512] = v1;
    __syncthreads();
    if (tid < 10) {
        float ssum = 0.f;
        for (int cc = 0; cc < 64; ++cc) ssum += scr[tid * 64 + cc];
        atomicAdd(energy + ((blockIdx.x >> 4) * 10) + tid, ssum);
    }
}

__global__ void k_readout(const float* __restrict__ ws,
                          const float* __restrict__ W,
                          const float* __restrict__ bias,
                          float* __restrict__ out) {
    int i = blockIdx.x * 256 + threadIdx.x;
    if (i < 1280) {
        int b = i / 10, o = i % 10;
        float s = bias[o];
#pragma unroll
        for (int f = 0; f < 10; ++f) {
            float feat = log1pf(ws[WS_ENERGY + b * 10 + f] + 1e-8f);
            s = fmaf(feat, W[o * 10 + f], s);
        }
        out[i] = s;
    }
}

extern "C" void kernel_launch(void* const* d_in, const int* in_sizes, int n_in,
                              void* d_out, int out_size, void* d_ws, size_t ws_size,
                              hipStream_t stream) {
    const float* images = (const float*)d_in[0];
    const float* conn_r = (const float*)d_in[1];
    const float* conn_i = (const float*)d_in[2];
    const float* phase  = (const float*)d_in[3];
    const float* gain   = (const float*)d_in[4];
    const float* W      = (const float*)d_in[5];
    const float* bias   = (const float*)d_in[6];
    float* ws  = (float*)d_ws;
    float* out = (float*)d_out;

    hipLaunchKernelGGL(k_init, dim3(6), dim3(256), 0, stream, ws);
    hipLaunchKernelGGL(k_max, dim3(98), dim3(256), 0, stream, images, ws, 128 * 28 * 28);
    hipLaunchKernelGGL(k_prep, dim3(493), dim3(256), 0, stream,
                       images, conn_r, conn_i, phase, gain, ws);
    hipLaunchKernelGGL(k_main, dim3(2048), dim3(512), 0, stream, ws, ws + WS_ENERGY);
    hipLaunchKernelGGL(k_readout, dim3(5), dim3(256), 0, stream, ws, W, bias, out);
}

// Round 8
// 524.943 us; speedup vs baseline: 7.3952x; 7.3952x over previous
//
#include <hip/hip_runtime.h>
#include <cmath>

// PhaseAwareClassifier on MI355X — R8: pure-bf16 complex MFMA GEMM.
// R7 post-mortem: 12-MFMA split + 6 A-mats fully unrolled -> register demand
// >> 128 -> scratch spills (8.9GB fetch). Fix: pure bf16 (O is re-rounded
// from exact fp32 acc every step so rounding noise doesn't compound; est.
// logit err ~5e-3 vs 4.3e-2 threshold). 4 MFMAs/position, 2 conn mats,
// kt-loop unroll(1). LDS 43.5KB -> 2 blocks/CU. Energy taken from exact
// fp32 registers at the last step (not bf16 LDS).

#define NSTEPS  10
#define INJ_ST  4

typedef __bf16 bf16x8 __attribute__((ext_vector_type(8)));
typedef __bf16 bf16x4 __attribute__((ext_vector_type(4)));
typedef short  short8 __attribute__((ext_vector_type(8)));
typedef float  f32x4  __attribute__((ext_vector_type(4)));

// workspace layout (float offsets)
#define WS_MAX    0          // 1      enc_max (uint-ordered float)
#define WS_ENERGY 64         // 1280   energy[b][10]
#define WS_GSP    2048       // 160    softplus(gain), zero-padded
#define WS_CONN   4096       // 2 bf16 matrices [20][160][8] chunked: Cr, Ci
                             //   2*25600 bf16 = 25600 floats
#define WS_INJ    32768      // 100352 inj[b][49][16] = px * 1.02/enc_max

__global__ void k_init(float* ws) {
    int i = blockIdx.x * 256 + threadIdx.x;
    if (i == 0) ws[WS_MAX] = 0.f;
    if (i < 1280) ws[WS_ENERGY + i] = 0.f;
}

__global__ void k_max(const float* __restrict__ img, float* ws, int n) {
    __shared__ float sm[256];
    float v = 0.f;
    for (int i = blockIdx.x * blockDim.x + threadIdx.x; i < n; i += gridDim.x * blockDim.x)
        v = fmaxf(v, fabsf(img[i]));
    sm[threadIdx.x] = v;
    __syncthreads();
    for (int s = 128; s > 0; s >>= 1) {
        if (threadIdx.x < s) sm[threadIdx.x] = fmaxf(sm[threadIdx.x], sm[threadIdx.x + s]);
        __syncthreads();
    }
    if (threadIdx.x == 0)
        atomicMax((unsigned int*)(ws + WS_MAX), __float_as_uint(sm[0]));
}

__global__ void k_prep(const float* __restrict__ img,
                       const float* __restrict__ cr, const float* __restrict__ ci,
                       const float* __restrict__ phase, const float* __restrict__ gain,
                       float* ws) {
    int i = blockIdx.x * 256 + threadIdx.x;
    __bf16* Cb = (__bf16*)(ws + WS_CONN);
    if (i < 25600) {                       // (m=j row, k=s col) of A
        int m = i / 160, k = i % 160;
        float vr = 0.f, vi = 0.f;
        if (m < 131 && k < 131) {
            float a = cr[k * 131 + m], b = ci[k * 131 + m];
            float ph = phase[m];
            float cp = cosf(ph), sp = sinf(ph);
            vr = a * cp - b * sp;
            vi = a * sp + b * cp;
        }
        int ca = ((k >> 3) * 160 + m) * 8 + (k & 7);   // chunked addr
        Cb[ca]         = (__bf16)vr;
        Cb[25600 + ca] = (__bf16)vi;
    } else if (i < 25760) {
        int j = i - 25600;
        float g = 0.f;
        if (j < 131) {
            float x = gain[j];
            g = (x > 20.f) ? x : log1pf(expf(x));  // softplus
        }
        ws[WS_GSP + j] = g;                 // zero for padded rows -> out=0
    } else if (i < 25760 + 128 * 49 * 16) {
        int q = i - 25760;
        int m = q & 15, jj = (q >> 4) % 49, b = q / (49 * 16);
        int u = m >> 2, v2 = m & 3, pi = jj / 7, pj = jj % 7;
        float px = img[b * 784 + (pi * 4 + u) * 28 + (pj * 4 + v2)];
        float mx = ws[WS_MAX];
        float sc = (mx > 1e-8f) ? (1.02f / mx) : 1.02f;   // 0.85*4*0.3
        ws[WS_INJ + q] = px * sc;
    }
}

static __device__ __forceinline__ f32x4 MF(bf16x8 a, bf16x8 b, f32x4 c) {
    return __builtin_amdgcn_mfma_f32_16x16x32_bf16(a, b, c, 0, 0, 0);
}
static __device__ __forceinline__ bf16x8 bneg(bf16x8 a) {
    short8 t = __builtin_bit_cast(short8, a) ^ (short8)(short)0x8000;
    return __builtin_bit_cast(bf16x8, t);
}

__global__ __launch_bounds__(512, 2)
void k_main(const float* __restrict__ ws, float* __restrict__ energy) {
    // O state: 2 bf16 matrices chunked [c=20][n=64][8]: r, i
    __shared__ __bf16 OB[2][20 * 64 * 8];          // 40,960 B
    __shared__ float scrE[640];                    //  2,560 B -> 2 blocks/CU
    const int tid  = threadIdx.x;
    const int lane = tid & 63;
    const int ln15 = lane & 15;
    const int quad = lane >> 4;
    const int wv   = __builtin_amdgcn_readfirstlane(tid >> 6);  // 0..7
    const int ntile = wv & 3;
    const int mhalf = wv >> 2;
    const int nidx  = ntile * 16 + ln15;            // this lane's column 0..63
    const int c = blockIdx.x * 64 + nidx;
    const int b = c >> 10;
    const int l = (c >> 4) & 63;
    const int m = c & 15;
    const float wl = 1.0f - fabsf((float)l - 32.0f) * (1.0f / 64.0f);

    const __bf16* __restrict__ Cr  = (const __bf16*)(ws + WS_CONN);
    const __bf16* __restrict__ Ci  = Cr + 25600;
    const float* __restrict__ gsp  = ws + WS_GSP;
    const float* __restrict__ injb = ws + WS_INJ;

    __bf16* __restrict__ OBr = &OB[0][0];
    __bf16* __restrict__ OBi = &OB[1][0];

    f32x4 accr[5], acci[5];                         // acc == 4 * field
#pragma unroll
    for (int p = 0; p < 5; ++p) { accr[p] = (f32x4)0.f; acci[p] = (f32x4)0.f; }

    // zero O state
    {
        int* obi = (int*)&OB[0][0];
        for (int i = tid; i < 10240; i += 512) obi[i] = 0;
    }

    // injection: pre-scaled by 0.85*4*0.3, added AFTER the 0.85 decay mul
    auto inj_add = [&]() {
        if (mhalf == 0) {
#pragma unroll
            for (int p = 0; p < 4; ++p) {           // tiles 0..3 cover j<64
#pragma unroll
                for (int r = 0; r < 4; ++r) {
                    int j = p * 16 + quad * 4 + r;
                    if (j < 49) accr[p][r] += injb[(b * 49 + j) * 16 + m] * wl;
                }
            }
        }
    };

    // epilogue: out = tanh-rescale(0.25*acc) -> bf16 chunked LDS write.
    // On the last step, also stash exact fp32 |out|^2 for j in [121,130].
    auto epilogue = [&](bool last) {
#pragma unroll
        for (int p = 0; p < 5; ++p) {
            const int j0 = (mhalf * 5 + p) * 16 + quad * 4;
            float g4[4];
            *(float4*)g4 = *(const float4*)(gsp + j0);
            bf16x4 pr, pi;
#pragma unroll
            for (int r = 0; r < 4; ++r) {
                float fr = accr[p][r] * 0.25f;
                float fi = acci[p][r] * 0.25f;
                float mag = sqrtf(fr * fr + fi * fi + 1e-8f);
                float y = mag * g4[r];
                float e = __expf(-2.0f * y);
                float th = 1.0f - 2.0f * e * __builtin_amdgcn_rcpf(1.0f + e);
                float scv = th * __builtin_amdgcn_rcpf(mag + 1e-8f);
                float orv = fr * scv, oiv = fi * scv;
                pr[r] = (__bf16)orv; pi[r] = (__bf16)oiv;
                if (last && mhalf == 1 && (p == 2 || p == 3)) {
                    int j = j0 + r;
                    if (j >= 121 && j <= 130)
                        scrE[(j - 121) * 64 + nidx] = orv * orv + oiv * oiv;
                }
            }
            const int off = ((j0 >> 3) * 64 + nidx) * 8 + (j0 & 7);
            *(bf16x4*)(OBr + off) = pr;
            *(bf16x4*)(OBi + off) = pi;
        }
    };

    __syncthreads();
    inj_add();                                      // t = 0 (out is zero)
    epilogue(false);
    __syncthreads();

    for (int t = 1; t < NSTEPS; ++t) {
        // decay pre-scale + injection
#pragma unroll
        for (int p = 0; p < 5; ++p) { accr[p] *= 0.85f; acci[p] *= 0.85f; }
        if (t < INJ_ST) inj_add();

        // ---- MFMA: G += C * O (complex bf16, fp32 acc) ----
#pragma unroll 1
        for (int kt = 0; kt < 5; ++kt) {
            const int ch = kt * 4 + quad;           // this lane's k-chunk
            const int boff = (ch * 64 + nidx) * 8;
            bf16x8 b_r  = *(const bf16x8*)(OBr + boff);
            bf16x8 b_i  = *(const bf16x8*)(OBi + boff);
            bf16x8 b_ni = bneg(b_i);
#pragma unroll
            for (int p = 0; p < 5; ++p) {
                const int mr = (mhalf * 5 + p) * 16 + ln15;
                const int aoff = (ch * 160 + mr) * 8;
                bf16x8 a_r = *(const bf16x8*)(Cr + aoff);
                bf16x8 a_i = *(const bf16x8*)(Ci + aoff);
                f32x4 ar = accr[p], ai = acci[p];
                ar = MF(a_r, b_r,  ar);             // G_r += Cr*Or
                ar = MF(a_i, b_ni, ar);             // G_r -= Ci*Oi
                ai = MF(a_r, b_i,  ai);             // G_i += Cr*Oi
                ai = MF(a_i, b_r,  ai);             // G_i += Ci*Or
                accr[p] = ar; acci[p] = ai;
            }
        }
        __syncthreads();   // all reads of OB done
        epilogue(t == NSTEPS - 1);
        __syncthreads();   // OB ready for next step
    }

    // ---- energy: scrE[10][64] holds exact fp32 |out|^2 ----
    if (tid < 10) {
        float ssum = 0.f;
        for (int cc = 0; cc < 64; ++cc) ssum += scrE[tid * 64 + cc];
        atomicAdd(energy + (blockIdx.x >> 4) * 10 + tid, ssum);
    }
}

__global__ void k_readout(const float* __restrict__ ws,
                          const float* __restrict__ W,
                          const float* __restrict__ bias,
                          float* __restrict__ out) {
    int i = blockIdx.x * 256 + threadIdx.x;
    if (i < 1280) {
        int b = i / 10, o = i % 10;
        float s = bias[o];
#pragma unroll
        for (int f = 0; f < 10; ++f) {
            float feat = log1pf(ws[WS_ENERGY + b * 10 + f] + 1e-8f);
            s = fmaf(feat, W[o * 10 + f], s);
        }
        out[i] = s;
    }
}

extern "C" void kernel_launch(void* const* d_in, const int* in_sizes, int n_in,
                              void* d_out, int out_size, void* d_ws, size_t ws_size,
                              hipStream_t stream) {
    const float* images = (const float*)d_in[0];
    const float* conn_r = (const float*)d_in[1];
    const float* conn_i = (const float*)d_in[2];
    const float* phase  = (const float*)d_in[3];
    const float* gain   = (const float*)d_in[4];
    const float* W      = (const float*)d_in[5];
    const float* bias   = (const float*)d_in[6];
    float* ws  = (float*)d_ws;
    float* out = (float*)d_out;

    hipLaunchKernelGGL(k_init, dim3(6), dim3(256), 0, stream, ws);
    hipLaunchKernelGGL(k_max, dim3(98), dim3(256), 0, stream, images, ws, 128 * 28 * 28);
    hipLaunchKernelGGL(k_prep, dim3(493), dim3(256), 0, stream,
                       images, conn_r, conn_i, phase, gain, ws);
    hipLaunchKernelGGL(k_main, dim3(2048), dim3(512), 0, stream, ws, ws + WS_ENERGY);
    hipLaunchKernelGGL(k_readout, dim3(5), dim3(256), 0, stream, ws, W, bias, out);
}

// Round 9
// 459.392 us; speedup vs baseline: 8.4505x; 1.1427x over previous
//
#include <hip/hip_runtime.h>
#include <cmath>

// PhaseAwareClassifier on MI355X — R9: conn staged in LDS.
// R8 post-mortem: A-fragments re-streamed from global each step -> TA/L1
// bound (~190us of vmem issue), L1 thrashed by 2 blocks/CU (41KB window vs
// 32KB). Fix: conn (100KB, 2 bf16 mats chunked [ch][m][8]) -> LDS once per
// block, reused for all 9 GEMM steps. LDS total 145,920B -> 1 block/CU.
// Math identical to R8 (passed, absmax 7.8e-3): acc == 4*field invariant,
// pure-bf16 complex GEMM, 4 MFMAs/position, energy from exact fp32 regs.

#define NSTEPS  10
#define INJ_ST  4

typedef __bf16 bf16x8 __attribute__((ext_vector_type(8)));
typedef __bf16 bf16x4 __attribute__((ext_vector_type(4)));
typedef short  short8 __attribute__((ext_vector_type(8)));
typedef float  f32x4  __attribute__((ext_vector_type(4)));

// workspace layout (float offsets)
#define WS_MAX    0          // 1      enc_max (uint-ordered float)
#define WS_ENERGY 64         // 1280   energy[b][10]
#define WS_GSP    2048       // 160    softplus(gain), zero-padded
#define WS_CONN   4096       // 2 bf16 matrices [20][160][8] chunked: Cr, Ci
#define WS_INJ    32768      // 100352 inj[b][49][16] = px * 1.02/enc_max

__global__ void k_init(float* ws) {
    int i = blockIdx.x * 256 + threadIdx.x;
    if (i == 0) ws[WS_MAX] = 0.f;
    if (i < 1280) ws[WS_ENERGY + i] = 0.f;
}

__global__ void k_max(const float* __restrict__ img, float* ws, int n) {
    __shared__ float sm[256];
    float v = 0.f;
    for (int i = blockIdx.x * blockDim.x + threadIdx.x; i < n; i += gridDim.x * blockDim.x)
        v = fmaxf(v, fabsf(img[i]));
    sm[threadIdx.x] = v;
    __syncthreads();
    for (int s = 128; s > 0; s >>= 1) {
        if (threadIdx.x < s) sm[threadIdx.x] = fmaxf(sm[threadIdx.x], sm[threadIdx.x + s]);
        __syncthreads();
    }
    if (threadIdx.x == 0)
        atomicMax((unsigned int*)(ws + WS_MAX), __float_as_uint(sm[0]));
}

__global__ void k_prep(const float* __restrict__ img,
                       const float* __restrict__ cr, const float* __restrict__ ci,
                       const float* __restrict__ phase, const float* __restrict__ gain,
                       float* ws) {
    int i = blockIdx.x * 256 + threadIdx.x;
    __bf16* Cb = (__bf16*)(ws + WS_CONN);
    if (i < 25600) {                       // (m=j row, k=s col) of A
        int m = i / 160, k = i % 160;
        float vr = 0.f, vi = 0.f;
        if (m < 131 && k < 131) {
            float a = cr[k * 131 + m], b = ci[k * 131 + m];
            float ph = phase[m];
            float cp = cosf(ph), sp = sinf(ph);
            vr = a * cp - b * sp;
            vi = a * sp + b * cp;
        }
        int ca = ((k >> 3) * 160 + m) * 8 + (k & 7);   // chunked addr
        Cb[ca]         = (__bf16)vr;
        Cb[25600 + ca] = (__bf16)vi;
    } else if (i < 25760) {
        int j = i - 25600;
        float g = 0.f;
        if (j < 131) {
            float x = gain[j];
            g = (x > 20.f) ? x : log1pf(expf(x));  // softplus
        }
        ws[WS_GSP + j] = g;                 // zero for padded rows -> out=0
    } else if (i < 25760 + 128 * 49 * 16) {
        int q = i - 25760;
        int m = q & 15, jj = (q >> 4) % 49, b = q / (49 * 16);
        int u = m >> 2, v2 = m & 3, pi = jj / 7, pj = jj % 7;
        float px = img[b * 784 + (pi * 4 + u) * 28 + (pj * 4 + v2)];
        float mx = ws[WS_MAX];
        float sc = (mx > 1e-8f) ? (1.02f / mx) : 1.02f;   // 0.85*4*0.3
        ws[WS_INJ + q] = px * sc;
    }
}

static __device__ __forceinline__ f32x4 MF(bf16x8 a, bf16x8 b, f32x4 c) {
    return __builtin_amdgcn_mfma_f32_16x16x32_bf16(a, b, c, 0, 0, 0);
}
static __device__ __forceinline__ bf16x8 bneg(bf16x8 a) {
    short8 t = __builtin_bit_cast(short8, a) ^ (short8)(short)0x8000;
    return __builtin_bit_cast(bf16x8, t);
}

__global__ __launch_bounds__(512, 1)
void k_main(const float* __restrict__ ws, float* __restrict__ energy) {
    __shared__ __bf16 CL[2 * 25600];               // 102,400 B: Cr, Ci chunked
    __shared__ __bf16 OB[2][20 * 64 * 8];          //  40,960 B: Or, Oi chunked
    __shared__ float scrE[640];                    //   2,560 B -> total 145,920
    const int tid  = threadIdx.x;
    const int lane = tid & 63;
    const int ln15 = lane & 15;
    const int quad = lane >> 4;
    const int wv   = __builtin_amdgcn_readfirstlane(tid >> 6);  // 0..7
    const int ntile = wv & 3;
    const int mhalf = wv >> 2;
    const int nidx  = ntile * 16 + ln15;            // this lane's column 0..63
    const int c = blockIdx.x * 64 + nidx;
    const int b = c >> 10;
    const int l = (c >> 4) & 63;
    const int m = c & 15;
    const float wl = 1.0f - fabsf((float)l - 32.0f) * (1.0f / 64.0f);

    const float* __restrict__ gsp  = ws + WS_GSP;
    const float* __restrict__ injb = ws + WS_INJ;

    // stage conn: 102,400 B global -> LDS, once (reused 9 steps)
    {
        const int4* __restrict__ src = (const int4*)(ws + WS_CONN);
        int4* dst = (int4*)CL;
        for (int i = tid; i < 6400; i += 512) dst[i] = src[i];
    }
    const __bf16* __restrict__ Cr = CL;
    const __bf16* __restrict__ Ci = CL + 25600;

    __bf16* __restrict__ OBr = &OB[0][0];
    __bf16* __restrict__ OBi = &OB[1][0];

    f32x4 accr[5], acci[5];                         // acc == 4 * field
#pragma unroll
    for (int p = 0; p < 5; ++p) { accr[p] = (f32x4)0.f; acci[p] = (f32x4)0.f; }

    // zero O state
    {
        int* obi = (int*)&OB[0][0];
        for (int i = tid; i < 10240; i += 512) obi[i] = 0;
    }

    // injection: pre-scaled by 0.85*4*0.3, added AFTER the 0.85 decay mul
    auto inj_add = [&]() {
        if (mhalf == 0) {
#pragma unroll
            for (int p = 0; p < 4; ++p) {           // tiles 0..3 cover j<64
#pragma unroll
                for (int r = 0; r < 4; ++r) {
                    int j = p * 16 + quad * 4 + r;
                    if (j < 49) accr[p][r] += injb[(b * 49 + j) * 16 + m] * wl;
                }
            }
        }
    };

    // epilogue: out = tanh-rescale(0.25*acc) -> bf16 chunked LDS write.
    // On the last step, also stash exact fp32 |out|^2 for j in [121,130].
    auto epilogue = [&](bool last) {
#pragma unroll
        for (int p = 0; p < 5; ++p) {
            const int j0 = (mhalf * 5 + p) * 16 + quad * 4;
            float g4[4];
            *(float4*)g4 = *(const float4*)(gsp + j0);
            bf16x4 pr, pi;
#pragma unroll
            for (int r = 0; r < 4; ++r) {
                float fr = accr[p][r] * 0.25f;
                float fi = acci[p][r] * 0.25f;
                float mag = sqrtf(fr * fr + fi * fi + 1e-8f);
                float y = mag * g4[r];
                float e = __expf(-2.0f * y);
                float th = 1.0f - 2.0f * e * __builtin_amdgcn_rcpf(1.0f + e);
                float scv = th * __builtin_amdgcn_rcpf(mag + 1e-8f);
                float orv = fr * scv, oiv = fi * scv;
                pr[r] = (__bf16)orv; pi[r] = (__bf16)oiv;
                if (last && mhalf == 1 && (p == 2 || p == 3)) {
                    int j = j0 + r;
                    if (j >= 121 && j <= 130)
                        scrE[(j - 121) * 64 + nidx] = orv * orv + oiv * oiv;
                }
            }
            const int off = ((j0 >> 3) * 64 + nidx) * 8 + (j0 & 7);
            *(bf16x4*)(OBr + off) = pr;
            *(bf16x4*)(OBi + off) = pi;
        }
    };

    __syncthreads();
    inj_add();                                      // t = 0 (out is zero)
    epilogue(false);
    __syncthreads();

    for (int t = 1; t < NSTEPS; ++t) {
        // decay pre-scale + injection
#pragma unroll
        for (int p = 0; p < 5; ++p) { accr[p] *= 0.85f; acci[p] *= 0.85f; }
        if (t < INJ_ST) inj_add();

        // ---- MFMA: G += C * O (complex bf16, fp32 acc; A and B from LDS) --
#pragma unroll 1
        for (int kt = 0; kt < 5; ++kt) {
            const int ch = kt * 4 + quad;           // this lane's k-chunk
            const int boff = (ch * 64 + nidx) * 8;
            bf16x8 b_r  = *(const bf16x8*)(OBr + boff);
            bf16x8 b_i  = *(const bf16x8*)(OBi + boff);
            bf16x8 b_ni = bneg(b_i);
#pragma unroll
            for (int p = 0; p < 5; ++p) {
                const int mr = (mhalf * 5 + p) * 16 + ln15;
                const int aoff = (ch * 160 + mr) * 8;
                bf16x8 a_r = *(const bf16x8*)(Cr + aoff);
                bf16x8 a_i = *(const bf16x8*)(Ci + aoff);
                f32x4 ar = accr[p], ai = acci[p];
                ar = MF(a_r, b_r,  ar);             // G_r += Cr*Or
                ar = MF(a_i, b_ni, ar);             // G_r -= Ci*Oi
                ai = MF(a_r, b_i,  ai);             // G_i += Cr*Oi
                ai = MF(a_i, b_r,  ai);             // G_i += Ci*Or
                accr[p] = ar; acci[p] = ai;
            }
        }
        __syncthreads();   // all reads of OB done
        epilogue(t == NSTEPS - 1);
        __syncthreads();   // OB ready for next step
    }

    // ---- energy: scrE[10][64] holds exact fp32 |out|^2 ----
    if (tid < 10) {
        float ssum = 0.f;
        for (int cc = 0; cc < 64; ++cc) ssum += scrE[tid * 64 + cc];
        atomicAdd(energy + (blockIdx.x >> 4) * 10 + tid, ssum);
    }
}

__global__ void k_readout(const float* __restrict__ ws,
                          const float* __restrict__ W,
                          const float* __restrict__ bias,
                          float* __restrict__ out) {
    int i = blockIdx.x * 256 + threadIdx.x;
    if (i < 1280) {
        int b = i / 10, o = i % 10;
        float s = bias[o];
#pragma unroll
        for (int f = 0; f < 10; ++f) {
            float feat = log1pf(ws[WS_ENERGY + b * 10 + f] + 1e-8f);
            s = fmaf(feat, W[o * 10 + f], s);
        }
        out[i] = s;
    }
}

extern "C" void kernel_launch(void* const* d_in, const int* in_sizes, int n_in,
                              void* d_out, int out_size, void* d_ws, size_t ws_size,
                              hipStream_t stream) {
    const float* images = (const float*)d_in[0];
    const float* conn_r = (const float*)d_in[1];
    const float* conn_i = (const float*)d_in[2];
    const float* phase  = (const float*)d_in[3];
    const float* gain   = (const float*)d_in[4];
    const float* W      = (const float*)d_in[5];
    const float* bias   = (const float*)d_in[6];
    float* ws  = (float*)d_ws;
    float* out = (float*)d_out;

    hipLaunchKernelGGL(k_init, dim3(6), dim3(256), 0, stream, ws);
    hipLaunchKernelGGL(k_max, dim3(98), dim3(256), 0, stream, images, ws, 128 * 28 * 28);
    hipLaunchKernelGGL(k_prep, dim3(493), dim3(256), 0, stream,
                       images, conn_r, conn_i, phase, gain, ws);
    hipLaunchKernelGGL(k_main, dim3(2048), dim3(512), 0, stream, ws, ws + WS_ENERGY);
    hipLaunchKernelGGL(k_readout, dim3(5), dim3(256), 0, stream, ws, W, bias, out);
}